// Round 12
// baseline (378.176 us; speedup 1.0000x reference)
//
#include <hip/hip_runtime.h>
#include <hip/hip_bf16.h>

// MHCtxAttention: N=32, T=1500, ENC=1024, DEC=1024, A=512, H=4, HA=2048
// Outputs: ali (N*H*T = 192000 f32), ctx (N*1024 = 32768 f32), concat in d_out.

#define N_B   32
#define T_S   1500
#define ENC_D 1024
#define HA_D  2048
#define A_D   512
#define H_N   4
#define MROWS 48000   // N_B * T_S

typedef short s8v  __attribute__((ext_vector_type(8)));
typedef float f32x4 __attribute__((ext_vector_type(4)));

__device__ __forceinline__ unsigned short f2bf(float f) {
    unsigned u = __float_as_uint(f);
    unsigned r = (u + 0x7FFFu + ((u >> 16) & 1u)) >> 16;
    return (unsigned short)r;
}
__device__ __forceinline__ float bf2f(unsigned short b) {
    return __uint_as_float(((unsigned)b) << 16);
}
__device__ __forceinline__ float fast_tanh(float x) {
    float e2 = __expf(2.0f * x);
    return 1.0f - __fdividef(2.0f, e2 + 1.0f);
}
__device__ __forceinline__ void gload_lds16(const void* g, void* l) {
    __builtin_amdgcn_global_load_lds(
        (const unsigned int __attribute__((address_space(1)))*)g,
        (unsigned int __attribute__((address_space(3)))*)l, 16, 0, 0);
}

// ============ skinny GEMM body: Y[n][c] (+)= sum_k X[n][k] * W[k][c]  (M=32) ============
__device__ __forceinline__ void skinny_body(
    int bid, const float* __restrict__ X, const float* __restrict__ W,
    const float* __restrict__ bias, float* __restrict__ Y,
    int Ncols, int ct_mask, int ct_shift, int xA, int xB, float* xT /* >= 64*36 floats */) {
    const int tid = threadIdx.x;
    const int ct = bid & ct_mask, ks = bid >> ct_shift;
    const int c0 = ct << 8, k0 = ks << 6;
    const int hsel = c0 >> 9;
    {
        const int n = tid >> 3, kk0 = (tid & 7) << 3;
        const float* xr = X + (size_t)n * xA + hsel * xB + k0 + kk0;
        float4 v0 = *(const float4*)xr;
        float4 v1 = *(const float4*)(xr + 4);
        xT[(kk0 + 0) * 36 + n] = v0.x;
        xT[(kk0 + 1) * 36 + n] = v0.y;
        xT[(kk0 + 2) * 36 + n] = v0.z;
        xT[(kk0 + 3) * 36 + n] = v0.w;
        xT[(kk0 + 4) * 36 + n] = v1.x;
        xT[(kk0 + 5) * 36 + n] = v1.y;
        xT[(kk0 + 6) * 36 + n] = v1.z;
        xT[(kk0 + 7) * 36 + n] = v1.w;
    }
    __syncthreads();
    const int w = tid >> 6, lane = tid & 63;
    f32x4 acc[8];
    if (bias != nullptr && ks == 0) {
        f32x4 bv = *(const f32x4*)&bias[c0 + (lane << 2)];
#pragma unroll
        for (int j = 0; j < 8; ++j) acc[j] = bv;
    } else {
#pragma unroll
        for (int j = 0; j < 8; ++j) { f32x4 z = {0.f, 0.f, 0.f, 0.f}; acc[j] = z; }
    }
    const float* Wp = W + (size_t)k0 * Ncols + c0 + (lane << 2);
#pragma unroll 4
    for (int kk = 0; kk < 64; ++kk) {
        f32x4 wf = *(const f32x4*)(Wp + (size_t)kk * Ncols);
        f32x4 xlo = *(const f32x4*)&xT[kk * 36 + w * 8];
        f32x4 xhi = *(const f32x4*)&xT[kk * 36 + w * 8 + 4];
#pragma unroll
        for (int j = 0; j < 4; ++j) {
            acc[j]     += xlo[j] * wf;
            acc[4 + j] += xhi[j] * wf;
        }
    }
#pragma unroll
    for (int j = 0; j < 8; ++j) {
        float* yp = Y + (size_t)(w * 8 + j) * Ncols + c0 + (lane << 2);
#pragma unroll
        for (int i = 0; i < 4; ++i) atomicAdd(yp + i, acc[j][i]);
    }
}

__global__ __launch_bounds__(256) void skinny_k(
    const float* __restrict__ X, const float* __restrict__ W,
    const float* __restrict__ bias, float* __restrict__ Y,
    int Ncols, int ct_mask, int ct_shift, int xA, int xB) {
    __shared__ float xT[64 * 36];
    skinny_body(blockIdx.x, X, W, bias, Y, Ncols, ct_mask, ct_shift, xA, xB, xT);
}

// ============ prep kernel ============
// [0,128)    dec_part: dp += dec_prev @ W_dec (k-split atomic skinny, dp pre-zeroed)
// [128,640)  W_key transpose-cast -> Wt
// [640,3648) cast enc_pad f32->bf16, skipping fully-masked 16-row chunks
__global__ __launch_bounds__(256) void prep_k(
    const float* __restrict__ enc_pad, const float* __restrict__ Wk,
    const float* __restrict__ dec_prev, const float* __restrict__ W_dec,
    const int* __restrict__ enc_len,
    unsigned short* __restrict__ Xb, unsigned short* __restrict__ Wt,
    float* __restrict__ dp) {
    __shared__ float shmem[64 * 65];
    const int b = blockIdx.x;
    const int tid = threadIdx.x;
    if (b < 128) {
        skinny_body(b, dec_prev, W_dec, nullptr, dp, HA_D, 7, 3, 1024, 0, shmem);
    } else if (b < 640) {
        float (*ld)[65] = (float(*)[65])shmem;
        const int bb = b - 128;
        const int tx = tid & 63, ty = tid >> 6;
        const int c0 = (bb & 31) * 64, d0 = (bb >> 5) * 64;
#pragma unroll
        for (int j = 0; j < 16; ++j)
            ld[ty + 4 * j][tx] = Wk[(size_t)(d0 + ty + 4 * j) * HA_D + c0 + tx];
        __syncthreads();
#pragma unroll
        for (int j = 0; j < 16; ++j)
            Wt[(size_t)(c0 + ty + 4 * j) * ENC_D + d0 + tx] = f2bf(ld[tx][ty + 4 * j]);
    } else {
        const int cb = b - 640;                 // 0..3007
        const int n = cb / 94, tch = cb - n * 94;
        const int t0 = tch * 16;
        if (t0 >= enc_len[n]) return;
        const int rmax = (1500 - t0 < 16) ? (1500 - t0) : 16;
        const float4* in = (const float4*)enc_pad + ((size_t)n * 1500 + t0) * 256;
        ushort4* out = (ushort4*)Xb + ((size_t)n * 1500 + t0) * 256;
#pragma unroll
        for (int it = 0; it < 16; ++it) {
            int j = it * 256 + tid;
            if ((j >> 8) < rmax) {
                float4 v = in[j];
                ushort4 o;
                o.x = f2bf(v.x); o.y = f2bf(v.y); o.z = f2bf(v.z); o.w = f2bf(v.w);
                out[j] = o;
            }
        }
    }
}

// ============ fused score GEMM: 128x128 tile (catalog-optimal aspect), 4 blocks/CU ============
// grid 6000 = 375 mtiles x 16 col-tiles.  e_out must be pre-zeroed (4 col-tiles add per head elem).
// 512 thr = 8 waves, wave grid 2(M) x 4(N), per-wave 64x32, acc 4x2 frags (32 VGPR).
// LDS 33 KB -> 4 blocks/CU, 32 waves/CU (full). __launch_bounds__(512,8) caps VGPR at 64.
__global__ __launch_bounds__(512, 8) void fused_score_k(
    const unsigned short* __restrict__ Xb, const unsigned short* __restrict__ Wt,
    const float* __restrict__ dec, const float* __restrict__ wconv,
    const int* __restrict__ enc_len, float* __restrict__ e_out) {
    __shared__ unsigned short As[128 * 64];   // 16 KB
    __shared__ unsigned short Bs[128 * 64];   // 16 KB
    __shared__ float e_s[128];

    const int tid = threadIdx.x;
    const int lane = tid & 63, wid = tid >> 6;
    const int wr = wid >> 2, wc = wid & 3;          // wave grid 2 (M) x 4 (N)
    const int l15 = lane & 15, lhi = lane >> 4;

    // bijective XCD swizzle: 6000 = 8 * 750; 16 consecutive wgids share one mtile (A-panel on-XCD)
    int orig = blockIdx.x;
    int wgid = (orig & 7) * 750 + (orig >> 3);
    const int mtile = wgid >> 4, nt = wgid & 15;
    const int r0 = mtile * 128;
    const int bcol0 = nt * 128;                     // global HA column base
    const int h = nt >> 2;

    // early-out: whole 128-row stripe masked
    {
        int n0 = (int)((unsigned)r0 / 1500u);
        int t0 = r0 - n0 * 1500;
        if (t0 + 127 < 1500 && t0 >= enc_len[n0]) return;
    }

    if (tid < 128) e_s[tid] = 0.f;

    // hoisted stage pointers (source pre-swizzled, LDS dest linear); A and B same shape
    const unsigned short* aSrc[2]; int aDst[2];
    const unsigned short* bSrc[2]; int bDst[2];
#pragma unroll
    for (int ld = 0; ld < 2; ++ld) {
        int li = ld * 512 + tid, rc = li >> 3, c16 = li & 7;
        int csw = (c16 ^ (rc & 7)) << 3;
        aSrc[ld] = Xb + (size_t)(r0 + rc) * ENC_D + csw;
        bSrc[ld] = Wt + (size_t)(bcol0 + rc) * ENC_D + csw;
        aDst[ld] = li * 8;
        bDst[ld] = li * 8;
    }

    const int cA0 = (lhi * 8) ^ ((l15 & 7) << 3);
    const int cA1 = (32 + lhi * 8) ^ ((l15 & 7) << 3);
    const int arow = wr * 64 + l15;
    const int bcol = wc * 32 + l15;

    f32x4 acc[4][2];
#pragma unroll
    for (int m = 0; m < 4; ++m)
#pragma unroll
        for (int n2 = 0; n2 < 2; ++n2) {
            f32x4 z = {0.f, 0.f, 0.f, 0.f};
            acc[m][n2] = z;
        }

    for (int ks = 0; ks < 16; ++ks) {
        const int kb = ks << 6;
#pragma unroll
        for (int ld = 0; ld < 2; ++ld) gload_lds16(aSrc[ld] + kb, As + aDst[ld]);
#pragma unroll
        for (int ld = 0; ld < 2; ++ld) gload_lds16(bSrc[ld] + kb, Bs + bDst[ld]);
        __syncthreads();
#pragma unroll
        for (int kk = 0; kk < 2; ++kk) {
            const int cc = kk ? cA1 : cA0;
            s8v af[4], bv[2];
#pragma unroll
            for (int m = 0; m < 4; ++m)
                af[m] = *(const s8v*)&As[(arow + m * 16) * 64 + cc];
#pragma unroll
            for (int n2 = 0; n2 < 2; ++n2)
                bv[n2] = *(const s8v*)&Bs[(bcol + n2 * 16) * 64 + cc];
#pragma unroll
            for (int m = 0; m < 4; ++m)
#pragma unroll
                for (int n2 = 0; n2 < 2; ++n2)
                    acc[m][n2] = __builtin_amdgcn_mfma_f32_16x16x32_bf16(af[m], bv[n2], acc[m][n2], 0, 0, 0);
        }
        __syncthreads();
    }

    // fused epilogue: + dec, tanh, * w_conv, sum over 32 a-cols (butterfly over l15), LDS atomic
    float wv[2];
#pragma unroll
    for (int n2 = 0; n2 < 2; ++n2)
        wv[n2] = wconv[bcol0 + wc * 32 + n2 * 16 + l15];
#pragma unroll
    for (int m = 0; m < 4; ++m) {
#pragma unroll
        for (int rg = 0; rg < 4; ++rg) {
            int row_l = wr * 64 + m * 16 + lhi * 4 + rg;
            int grow = r0 + row_l;
            int nn = (int)((unsigned)grow / 1500u);
            const float* dsl = dec + (size_t)nn * HA_D + bcol0 + wc * 32 + l15;
            float s = 0.f;
#pragma unroll
            for (int n2 = 0; n2 < 2; ++n2) {
                float v = acc[m][n2][rg] + dsl[n2 * 16];
                s += wv[n2] * fast_tanh(v);
            }
            s += __shfl_xor(s, 1); s += __shfl_xor(s, 2);
            s += __shfl_xor(s, 4); s += __shfl_xor(s, 8);
            if (l15 == 0) atomicAdd(&e_s[row_l], s);
        }
    }
    __syncthreads();
    if (tid < 128) {
        int grow = r0 + tid;
        int nn = grow / 1500, tt = grow - nn * 1500;
        atomicAdd(&e_out[(size_t)(nn * H_N + h) * T_S + tt], e_s[tid]);
    }
}

// ============ fused softmax + weighted-enc reduction ============
// grid 640:
//  [0,512)   wenc blocks: b = n*16 + tq (94-t chunks). Recompute per-head (m, 1/Z) from e,
//            build p-chunk in LDS, accumulate wenc via atomics (wenc pre-zeroed).
//  [512,640) ali-writer blocks: bb = (n*4+h). Write ali output; also zero ctx region.
__global__ __launch_bounds__(256) void sm_wenc_k(
    const unsigned short* __restrict__ Xb, const float* __restrict__ e,
    const int* __restrict__ enc_len, float* __restrict__ ali,
    float* __restrict__ ctx_zero, float* __restrict__ wenc) {
    const int b = blockIdx.x, tid = threadIdx.x;
    const int lane = tid & 63, wv = tid >> 6;
    __shared__ float mzs[4][2];
    __shared__ float ps[4][94];
    __shared__ float red[4];
    if (b < 512) {
        const int n = b >> 4, tq = b & 15;
        const int len = enc_len[n];
        const int t0 = tq * 94;
        if (t0 >= len) return;                       // p == 0 there; wenc pre-zeroed
        const int tcnt = (t0 + 94 <= T_S) ? 94 : (T_S - t0);
        // wave wv reduces head wv's full row: m and Z
        {
            const float* erow = e + (size_t)(n * H_N + wv) * T_S;
            float ev[24];
            float mx = -__builtin_inff();
#pragma unroll
            for (int i = 0; i < 24; ++i) {
                int t = lane + i * 64;
                float v = (t < len) ? erow[t] : -__builtin_inff();
                ev[i] = v;
                mx = fmaxf(mx, v);
            }
#pragma unroll
            for (int o = 32; o; o >>= 1) mx = fmaxf(mx, __shfl_xor(mx, o));
            float Z = 0.f;
#pragma unroll
            for (int i = 0; i < 24; ++i) Z += __expf(ev[i] - mx);
#pragma unroll
            for (int o = 32; o; o >>= 1) Z += __shfl_xor(Z, o);
            if (lane == 0) { mzs[wv][0] = mx; mzs[wv][1] = 1.0f / Z; }
        }
        __syncthreads();
        // build p-chunk for all 4 heads
#pragma unroll
        for (int i = 0; i < 2; ++i) {
            int idx = tid + i * 256;                 // need 4*94 = 376
            if (idx < 376) {
                int hh = idx / 94, tt = idx - hh * 94;
                int t = t0 + tt;
                float v = 0.f;
                if (t < len)
                    v = __expf(e[(size_t)(n * H_N + hh) * T_S + t] - mzs[hh][0]) * mzs[hh][1];
                ps[hh][tt] = v;
            }
        }
        __syncthreads();
        const int d0 = tid * 4;
        float a[4][4] = {};
        const unsigned short* xp = Xb + (size_t)(n * T_S + t0) * ENC_D + d0;
#pragma unroll 4
        for (int t = 0; t < tcnt; ++t) {
            ushort4 xv = *(const ushort4*)&xp[(size_t)t * ENC_D];
            float x0 = bf2f(xv.x), x1 = bf2f(xv.y), x2 = bf2f(xv.z), x3 = bf2f(xv.w);
#pragma unroll
            for (int hh = 0; hh < 4; ++hh) {
                float al = ps[hh][t];
                a[hh][0] = fmaf(al, x0, a[hh][0]);
                a[hh][1] = fmaf(al, x1, a[hh][1]);
                a[hh][2] = fmaf(al, x2, a[hh][2]);
                a[hh][3] = fmaf(al, x3, a[hh][3]);
            }
        }
#pragma unroll
        for (int hh = 0; hh < 4; ++hh)
#pragma unroll
            for (int j = 0; j < 4; ++j)
                atomicAdd(&wenc[(size_t)(n * H_N + hh) * ENC_D + d0 + j], a[hh][j]);
    } else {
        const int bb = b - 512;                      // 0..127 = n*4 + h
        ctx_zero[bb * 256 + tid] = 0.f;
        const int n = bb >> 2;
        const int len = enc_len[n];
        const float* row = e + (size_t)bb * T_S;
        float* orow = ali + (size_t)bb * T_S;
        float p[6];
        float mx = -__builtin_inff();
#pragma unroll
        for (int i = 0; i < 6; ++i) {
            int t = tid + i * 256;
            float v = -__builtin_inff();
            if (t < T_S && t < len) v = row[t];
            p[i] = v;
            mx = fmaxf(mx, v);
        }
#pragma unroll
        for (int o = 32; o; o >>= 1) mx = fmaxf(mx, __shfl_xor(mx, o));
        if (lane == 0) red[wv] = mx;
        __syncthreads();
        mx = fmaxf(fmaxf(red[0], red[1]), fmaxf(red[2], red[3]));
        __syncthreads();
        float sum = 0.f;
#pragma unroll
        for (int i = 0; i < 6; ++i) {
            float qv = (p[i] == -__builtin_inff()) ? 0.f : __expf(p[i] - mx);
            p[i] = qv;
            sum += qv;
        }
#pragma unroll
        for (int o = 32; o; o >>= 1) sum += __shfl_xor(sum, o);
        if (lane == 0) red[wv] = sum;
        __syncthreads();
        sum = red[0] + red[1] + red[2] + red[3];
        float inv = 1.0f / sum;
#pragma unroll
        for (int i = 0; i < 6; ++i) {
            int t = tid + i * 256;
            if (t < T_S) orow[t] = p[i] * inv;
        }
    }
}

extern "C" void kernel_launch(void* const* d_in, const int* in_sizes, int n_in,
                              void* d_out, int out_size, void* d_ws, size_t ws_size,
                              hipStream_t stream) {
    const float* enc_pad  = (const float*)d_in[0];
    const int*   enc_len  = (const int*)d_in[1];
    const float* dec_prev = (const float*)d_in[2];
    // d_in[3] = ali_prev (unused by forward)
    const float* W_enc    = (const float*)d_in[4];
    const float* b_enc    = (const float*)d_in[5];
    const float* W_key    = (const float*)d_in[6];
    const float* W_dec    = (const float*)d_in[7];
    const float* W_ctx    = (const float*)d_in[8];
    const float* b_ctx    = (const float*)d_in[9];
    const float* w_conv   = (const float*)d_in[10];

    char* ws = (char*)d_ws;
    unsigned short* Xb = (unsigned short*)ws;                 // 48000*1024*2 = 98,304,000
    unsigned short* Wt = (unsigned short*)(ws + 98304000);    // 2048*1024*2 =  4,194,304
    // zero-range (one memset): dp | e | wenc | cpre, contiguous, 1,816,576 B
    float* dp   = (float*)(ws + 102498304);                   // 32*2048*4   =    262,144
    float* e    = (float*)(ws + 102760448);                   // 192000*4    =    768,000
    float* wenc = (float*)(ws + 103528448);                   // 131072*4    =    524,288
    float* cpre = (float*)(ws + 104052736);                   // 65536*4     =    262,144

    float* ali = (float*)d_out;            // 192000
    float* ctx = ((float*)d_out) + 192000; // 32768

    hipMemsetAsync(ws + 102498304, 0, 1816576, stream);
    prep_k<<<3648, 256, 0, stream>>>(enc_pad, W_key, dec_prev, W_dec, enc_len, Xb, Wt, dp);
    fused_score_k<<<6000, 512, 0, stream>>>(Xb, Wt, dp, w_conv, enc_len, e);
    sm_wenc_k<<<640, 256, 0, stream>>>(Xb, e, enc_len, ali, ctx, wenc);
    // ctxpre[n][col] = wenc[n, col>>9, :] @ W_enc[:, col] + b_enc:  8ct x 16ks
    skinny_k<<<128, 256, 0, stream>>>(wenc, W_enc, b_enc, cpre, HA_D, 7, 3, 4096, 1024);
    // ctx[n][j] = cpre[n,:] @ W_ctx[:, j] + b_ctx:  4ct x 32ks
    skinny_k<<<128, 256, 0, stream>>>(cpre, W_ctx, b_ctx, ctx, ENC_D, 3, 2, 2048, 0);
}

// Round 13
// 357.603 us; speedup vs baseline: 1.0575x; 1.0575x over previous
//
#include <hip/hip_runtime.h>
#include <hip/hip_bf16.h>

// MHCtxAttention: N=32, T=1500, ENC=1024, DEC=1024, A=512, H=4, HA=2048
// Outputs: ali (N*H*T = 192000 f32), ctx (N*1024 = 32768 f32), concat in d_out.
//
// Final configuration (R8/R11-proven):
//  prep_k      : dec_part k-split skinny + W_key transpose-cast + masked-skip f32->bf16 cast
//  fused_score : 128x256 tile, single-buffer LDS (49KB -> 3 blk/CU), global_load_lds w=16,
//                both-sides XOR swizzle (conflict-free), XCD-bijective swizzle, fused
//                tanh/w_conv/butterfly epilogue. 963 TF effective, MfmaUtil ~34%.
//  sm_wenc_k   : fused masked-softmax + ali-weighted enc reduction + ali/ctx-zero writer
//  skinny_k x2 : ctxpre / ctx projections (LDS-broadcast, k-split atomics)

#define N_B   32
#define T_S   1500
#define ENC_D 1024
#define HA_D  2048
#define A_D   512
#define H_N   4
#define MROWS 48000   // N_B * T_S

typedef short s8v  __attribute__((ext_vector_type(8)));
typedef float f32x4 __attribute__((ext_vector_type(4)));

__device__ __forceinline__ unsigned short f2bf(float f) {
    unsigned u = __float_as_uint(f);
    unsigned r = (u + 0x7FFFu + ((u >> 16) & 1u)) >> 16;
    return (unsigned short)r;
}
__device__ __forceinline__ float bf2f(unsigned short b) {
    return __uint_as_float(((unsigned)b) << 16);
}
__device__ __forceinline__ float fast_tanh(float x) {
    float e2 = __expf(2.0f * x);
    return 1.0f - __fdividef(2.0f, e2 + 1.0f);
}
__device__ __forceinline__ void gload_lds16(const void* g, void* l) {
    __builtin_amdgcn_global_load_lds(
        (const unsigned int __attribute__((address_space(1)))*)g,
        (unsigned int __attribute__((address_space(3)))*)l, 16, 0, 0);
}

// ============ skinny GEMM body: Y[n][c] (+)= sum_k X[n][k] * W[k][c]  (M=32) ============
__device__ __forceinline__ void skinny_body(
    int bid, const float* __restrict__ X, const float* __restrict__ W,
    const float* __restrict__ bias, float* __restrict__ Y,
    int Ncols, int ct_mask, int ct_shift, int xA, int xB, float* xT /* >= 64*36 floats */) {
    const int tid = threadIdx.x;
    const int ct = bid & ct_mask, ks = bid >> ct_shift;
    const int c0 = ct << 8, k0 = ks << 6;
    const int hsel = c0 >> 9;
    {
        const int n = tid >> 3, kk0 = (tid & 7) << 3;
        const float* xr = X + (size_t)n * xA + hsel * xB + k0 + kk0;
        float4 v0 = *(const float4*)xr;
        float4 v1 = *(const float4*)(xr + 4);
        xT[(kk0 + 0) * 36 + n] = v0.x;
        xT[(kk0 + 1) * 36 + n] = v0.y;
        xT[(kk0 + 2) * 36 + n] = v0.z;
        xT[(kk0 + 3) * 36 + n] = v0.w;
        xT[(kk0 + 4) * 36 + n] = v1.x;
        xT[(kk0 + 5) * 36 + n] = v1.y;
        xT[(kk0 + 6) * 36 + n] = v1.z;
        xT[(kk0 + 7) * 36 + n] = v1.w;
    }
    __syncthreads();
    const int w = tid >> 6, lane = tid & 63;
    f32x4 acc[8];
    if (bias != nullptr && ks == 0) {
        f32x4 bv = *(const f32x4*)&bias[c0 + (lane << 2)];
#pragma unroll
        for (int j = 0; j < 8; ++j) acc[j] = bv;
    } else {
#pragma unroll
        for (int j = 0; j < 8; ++j) { f32x4 z = {0.f, 0.f, 0.f, 0.f}; acc[j] = z; }
    }
    const float* Wp = W + (size_t)k0 * Ncols + c0 + (lane << 2);
#pragma unroll 4
    for (int kk = 0; kk < 64; ++kk) {
        f32x4 wf = *(const f32x4*)(Wp + (size_t)kk * Ncols);
        f32x4 xlo = *(const f32x4*)&xT[kk * 36 + w * 8];
        f32x4 xhi = *(const f32x4*)&xT[kk * 36 + w * 8 + 4];
#pragma unroll
        for (int j = 0; j < 4; ++j) {
            acc[j]     += xlo[j] * wf;
            acc[4 + j] += xhi[j] * wf;
        }
    }
#pragma unroll
    for (int j = 0; j < 8; ++j) {
        float* yp = Y + (size_t)(w * 8 + j) * Ncols + c0 + (lane << 2);
#pragma unroll
        for (int i = 0; i < 4; ++i) atomicAdd(yp + i, acc[j][i]);
    }
}

__global__ __launch_bounds__(256) void skinny_k(
    const float* __restrict__ X, const float* __restrict__ W,
    const float* __restrict__ bias, float* __restrict__ Y,
    int Ncols, int ct_mask, int ct_shift, int xA, int xB) {
    __shared__ float xT[64 * 36];
    skinny_body(blockIdx.x, X, W, bias, Y, Ncols, ct_mask, ct_shift, xA, xB, xT);
}

// ============ prep kernel ============
// [0,128)    dec_part: dp += dec_prev @ W_dec (k-split atomic skinny, dp pre-zeroed)
// [128,640)  W_key transpose-cast -> Wt
// [640,3648) cast enc_pad f32->bf16, skipping fully-masked 16-row chunks
__global__ __launch_bounds__(256) void prep_k(
    const float* __restrict__ enc_pad, const float* __restrict__ Wk,
    const float* __restrict__ dec_prev, const float* __restrict__ W_dec,
    const int* __restrict__ enc_len,
    unsigned short* __restrict__ Xb, unsigned short* __restrict__ Wt,
    float* __restrict__ dp) {
    __shared__ float shmem[64 * 65];
    const int b = blockIdx.x;
    const int tid = threadIdx.x;
    if (b < 128) {
        skinny_body(b, dec_prev, W_dec, nullptr, dp, HA_D, 7, 3, 1024, 0, shmem);
    } else if (b < 640) {
        float (*ld)[65] = (float(*)[65])shmem;
        const int bb = b - 128;
        const int tx = tid & 63, ty = tid >> 6;
        const int c0 = (bb & 31) * 64, d0 = (bb >> 5) * 64;
#pragma unroll
        for (int j = 0; j < 16; ++j)
            ld[ty + 4 * j][tx] = Wk[(size_t)(d0 + ty + 4 * j) * HA_D + c0 + tx];
        __syncthreads();
#pragma unroll
        for (int j = 0; j < 16; ++j)
            Wt[(size_t)(c0 + ty + 4 * j) * ENC_D + d0 + tx] = f2bf(ld[tx][ty + 4 * j]);
    } else {
        const int cb = b - 640;                 // 0..3007
        const int n = cb / 94, tch = cb - n * 94;
        const int t0 = tch * 16;
        if (t0 >= enc_len[n]) return;
        const int rmax = (1500 - t0 < 16) ? (1500 - t0) : 16;
        const float4* in = (const float4*)enc_pad + ((size_t)n * 1500 + t0) * 256;
        ushort4* out = (ushort4*)Xb + ((size_t)n * 1500 + t0) * 256;
#pragma unroll
        for (int it = 0; it < 16; ++it) {
            int j = it * 256 + tid;
            if ((j >> 8) < rmax) {
                float4 v = in[j];
                ushort4 o;
                o.x = f2bf(v.x); o.y = f2bf(v.y); o.z = f2bf(v.z); o.w = f2bf(v.w);
                out[j] = o;
            }
        }
    }
}

// ============ fused score GEMM (R5/R8-proven): 128x256 tile, single-buffer, 3 blocks/CU ====
// grid 3000 = 375 mtiles x 8 col-tiles.  e_out must be pre-zeroed.
__global__ __launch_bounds__(512) void fused_score_k(
    const unsigned short* __restrict__ Xb, const unsigned short* __restrict__ Wt,
    const float* __restrict__ dec, const float* __restrict__ wconv,
    const int* __restrict__ enc_len, float* __restrict__ e_out) {
    __shared__ unsigned short As[128 * 64];   // 16 KB
    __shared__ unsigned short Bs[256 * 64];   // 32 KB
    __shared__ float e_s[128];

    const int tid = threadIdx.x;
    const int lane = tid & 63, wid = tid >> 6;
    const int wr = wid >> 2, wc = wid & 3;          // wave grid 2 (M) x 4 (N)
    const int l15 = lane & 15, lhi = lane >> 4;

    // bijective XCD swizzle: 3000 = 8 * 375; 8 consecutive wgids share one mtile
    int orig = blockIdx.x;
    int wgid = (orig & 7) * 375 + (orig >> 3);
    const int mtile = wgid >> 3, nt = wgid & 7;
    const int r0 = mtile * 128;
    const int bcol0 = nt * 256;                     // global HA column base
    const int h = nt >> 1;

    // early-out: whole 128-row stripe masked
    {
        int n0 = (int)((unsigned)r0 / 1500u);
        int t0 = r0 - n0 * 1500;
        if (t0 + 127 < 1500 && t0 >= enc_len[n0]) return;
    }

    if (tid < 128) e_s[tid] = 0.f;

    // hoisted stage pointers (source pre-swizzled, LDS dest linear)
    const unsigned short* aSrc[2]; int aDst[2];
#pragma unroll
    for (int ld = 0; ld < 2; ++ld) {
        int li = ld * 512 + tid, rowL = li >> 3, c16 = li & 7;
        aSrc[ld] = Xb + (size_t)(r0 + rowL) * ENC_D + ((c16 ^ (rowL & 7)) << 3);
        aDst[ld] = li * 8;
    }
    const unsigned short* bSrc[4]; int bDst[4];
#pragma unroll
    for (int ld = 0; ld < 4; ++ld) {
        int li = ld * 512 + tid, colL = li >> 3, c16 = li & 7;
        bSrc[ld] = Wt + (size_t)(bcol0 + colL) * ENC_D + ((c16 ^ (colL & 7)) << 3);
        bDst[ld] = li * 8;
    }

    const int cA0 = (lhi * 8) ^ ((l15 & 7) << 3);
    const int cA1 = (32 + lhi * 8) ^ ((l15 & 7) << 3);
    const int arow = wr * 64 + l15;
    const int bcol = wc * 64 + l15;

    f32x4 acc[4][4];
#pragma unroll
    for (int m = 0; m < 4; ++m)
#pragma unroll
        for (int n2 = 0; n2 < 4; ++n2) {
            f32x4 z = {0.f, 0.f, 0.f, 0.f};
            acc[m][n2] = z;
        }

    for (int ks = 0; ks < 16; ++ks) {
        const int kb = ks << 6;
#pragma unroll
        for (int ld = 0; ld < 2; ++ld) gload_lds16(aSrc[ld] + kb, As + aDst[ld]);
#pragma unroll
        for (int ld = 0; ld < 4; ++ld) gload_lds16(bSrc[ld] + kb, Bs + bDst[ld]);
        __syncthreads();
#pragma unroll
        for (int kk = 0; kk < 2; ++kk) {
            const int cc = kk ? cA1 : cA0;
            s8v af[4], bv[4];
#pragma unroll
            for (int m = 0; m < 4; ++m)
                af[m] = *(const s8v*)&As[(arow + m * 16) * 64 + cc];
#pragma unroll
            for (int n2 = 0; n2 < 4; ++n2)
                bv[n2] = *(const s8v*)&Bs[(bcol + n2 * 16) * 64 + cc];
#pragma unroll
            for (int m = 0; m < 4; ++m)
#pragma unroll
                for (int n2 = 0; n2 < 4; ++n2)
                    acc[m][n2] = __builtin_amdgcn_mfma_f32_16x16x32_bf16(af[m], bv[n2], acc[m][n2], 0, 0, 0);
        }
        __syncthreads();
    }

    // fused epilogue: + dec, tanh, * w_conv, sum over a-cols (butterfly over l15), LDS atomic
    float wv[4];
#pragma unroll
    for (int n2 = 0; n2 < 4; ++n2)
        wv[n2] = wconv[bcol0 + wc * 64 + n2 * 16 + l15];
#pragma unroll
    for (int m = 0; m < 4; ++m) {
#pragma unroll
        for (int rg = 0; rg < 4; ++rg) {
            int row_l = wr * 64 + m * 16 + lhi * 4 + rg;
            int grow = r0 + row_l;
            int nn = (int)((unsigned)grow / 1500u);
            const float* dsl = dec + (size_t)nn * HA_D + bcol0 + wc * 64 + l15;
            float s = 0.f;
#pragma unroll
            for (int n2 = 0; n2 < 4; ++n2) {
                float v = acc[m][n2][rg] + dsl[n2 * 16];
                s += wv[n2] * fast_tanh(v);
            }
            s += __shfl_xor(s, 1); s += __shfl_xor(s, 2);
            s += __shfl_xor(s, 4); s += __shfl_xor(s, 8);
            if (l15 == 0) atomicAdd(&e_s[row_l], s);
        }
    }
    __syncthreads();
    if (tid < 128) {
        int grow = r0 + tid;
        int nn = grow / 1500, tt = grow - nn * 1500;
        atomicAdd(&e_out[(size_t)(nn * H_N + h) * T_S + tt], e_s[tid]);
    }
}

// ============ fused softmax + weighted-enc reduction ============
// grid 640:
//  [0,512)   wenc blocks: b = n*16 + tq (94-t chunks). Recompute per-head (m, 1/Z) from e,
//            build p-chunk in LDS, accumulate wenc via atomics (wenc pre-zeroed).
//  [512,640) ali-writer blocks: bb = (n*4+h). Write ali output; also zero ctx region.
__global__ __launch_bounds__(256) void sm_wenc_k(
    const unsigned short* __restrict__ Xb, const float* __restrict__ e,
    const int* __restrict__ enc_len, float* __restrict__ ali,
    float* __restrict__ ctx_zero, float* __restrict__ wenc) {
    const int b = blockIdx.x, tid = threadIdx.x;
    const int lane = tid & 63, wv = tid >> 6;
    __shared__ float mzs[4][2];
    __shared__ float ps[4][94];
    __shared__ float red[4];
    if (b < 512) {
        const int n = b >> 4, tq = b & 15;
        const int len = enc_len[n];
        const int t0 = tq * 94;
        if (t0 >= len) return;                       // p == 0 there; wenc pre-zeroed
        const int tcnt = (t0 + 94 <= T_S) ? 94 : (T_S - t0);
        // wave wv reduces head wv's full row: m and Z
        {
            const float* erow = e + (size_t)(n * H_N + wv) * T_S;
            float ev[24];
            float mx = -__builtin_inff();
#pragma unroll
            for (int i = 0; i < 24; ++i) {
                int t = lane + i * 64;
                float v = (t < len) ? erow[t] : -__builtin_inff();
                ev[i] = v;
                mx = fmaxf(mx, v);
            }
#pragma unroll
            for (int o = 32; o; o >>= 1) mx = fmaxf(mx, __shfl_xor(mx, o));
            float Z = 0.f;
#pragma unroll
            for (int i = 0; i < 24; ++i) Z += __expf(ev[i] - mx);
#pragma unroll
            for (int o = 32; o; o >>= 1) Z += __shfl_xor(Z, o);
            if (lane == 0) { mzs[wv][0] = mx; mzs[wv][1] = 1.0f / Z; }
        }
        __syncthreads();
        // build p-chunk for all 4 heads
#pragma unroll
        for (int i = 0; i < 2; ++i) {
            int idx = tid + i * 256;                 // need 4*94 = 376
            if (idx < 376) {
                int hh = idx / 94, tt = idx - hh * 94;
                int t = t0 + tt;
                float v = 0.f;
                if (t < len)
                    v = __expf(e[(size_t)(n * H_N + hh) * T_S + t] - mzs[hh][0]) * mzs[hh][1];
                ps[hh][tt] = v;
            }
        }
        __syncthreads();
        const int d0 = tid * 4;
        float a[4][4] = {};
        const unsigned short* xp = Xb + (size_t)(n * T_S + t0) * ENC_D + d0;
#pragma unroll 4
        for (int t = 0; t < tcnt; ++t) {
            ushort4 xv = *(const ushort4*)&xp[(size_t)t * ENC_D];
            float x0 = bf2f(xv.x), x1 = bf2f(xv.y), x2 = bf2f(xv.z), x3 = bf2f(xv.w);
#pragma unroll
            for (int hh = 0; hh < 4; ++hh) {
                float al = ps[hh][t];
                a[hh][0] = fmaf(al, x0, a[hh][0]);
                a[hh][1] = fmaf(al, x1, a[hh][1]);
                a[hh][2] = fmaf(al, x2, a[hh][2]);
                a[hh][3] = fmaf(al, x3, a[hh][3]);
            }
        }
#pragma unroll
        for (int hh = 0; hh < 4; ++hh)
#pragma unroll
            for (int j = 0; j < 4; ++j)
                atomicAdd(&wenc[(size_t)(n * H_N + hh) * ENC_D + d0 + j], a[hh][j]);
    } else {
        const int bb = b - 512;                      // 0..127 = n*4 + h
        ctx_zero[bb * 256 + tid] = 0.f;
        const int n = bb >> 2;
        const int len = enc_len[n];
        const float* row = e + (size_t)bb * T_S;
        float* orow = ali + (size_t)bb * T_S;
        float p[6];
        float mx = -__builtin_inff();
#pragma unroll
        for (int i = 0; i < 6; ++i) {
            int t = tid + i * 256;
            float v = -__builtin_inff();
            if (t < T_S && t < len) v = row[t];
            p[i] = v;
            mx = fmaxf(mx, v);
        }
#pragma unroll
        for (int o = 32; o; o >>= 1) mx = fmaxf(mx, __shfl_xor(mx, o));
        if (lane == 0) red[wv] = mx;
        __syncthreads();
        mx = fmaxf(fmaxf(red[0], red[1]), fmaxf(red[2], red[3]));
        __syncthreads();
        float sum = 0.f;
#pragma unroll
        for (int i = 0; i < 6; ++i) {
            float qv = (p[i] == -__builtin_inff()) ? 0.f : __expf(p[i] - mx);
            p[i] = qv;
            sum += qv;
        }
#pragma unroll
        for (int o = 32; o; o >>= 1) sum += __shfl_xor(sum, o);
        if (lane == 0) red[wv] = sum;
        __syncthreads();
        sum = red[0] + red[1] + red[2] + red[3];
        float inv = 1.0f / sum;
#pragma unroll
        for (int i = 0; i < 6; ++i) {
            int t = tid + i * 256;
            if (t < T_S) orow[t] = p[i] * inv;
        }
    }
}

extern "C" void kernel_launch(void* const* d_in, const int* in_sizes, int n_in,
                              void* d_out, int out_size, void* d_ws, size_t ws_size,
                              hipStream_t stream) {
    const float* enc_pad  = (const float*)d_in[0];
    const int*   enc_len  = (const int*)d_in[1];
    const float* dec_prev = (const float*)d_in[2];
    // d_in[3] = ali_prev (unused by forward)
    const float* W_enc    = (const float*)d_in[4];
    const float* b_enc    = (const float*)d_in[5];
    const float* W_key    = (const float*)d_in[6];
    const float* W_dec    = (const float*)d_in[7];
    const float* W_ctx    = (const float*)d_in[8];
    const float* b_ctx    = (const float*)d_in[9];
    const float* w_conv   = (const float*)d_in[10];

    char* ws = (char*)d_ws;
    unsigned short* Xb = (unsigned short*)ws;                 // 48000*1024*2 = 98,304,000
    unsigned short* Wt = (unsigned short*)(ws + 98304000);    // 2048*1024*2 =  4,194,304
    // zero-range (one memset): dp | e | wenc | cpre, contiguous, 1,816,576 B
    float* dp   = (float*)(ws + 102498304);                   // 32*2048*4   =    262,144
    float* e    = (float*)(ws + 102760448);                   // 192000*4    =    768,000
    float* wenc = (float*)(ws + 103528448);                   // 131072*4    =    524,288
    float* cpre = (float*)(ws + 104052736);                   // 65536*4     =    262,144

    float* ali = (float*)d_out;            // 192000
    float* ctx = ((float*)d_out) + 192000; // 32768

    hipMemsetAsync(ws + 102498304, 0, 1816576, stream);
    prep_k<<<3648, 256, 0, stream>>>(enc_pad, W_key, dec_prev, W_dec, enc_len, Xb, Wt, dp);
    fused_score_k<<<3000, 512, 0, stream>>>(Xb, Wt, dp, w_conv, enc_len, e);
    sm_wenc_k<<<640, 256, 0, stream>>>(Xb, e, enc_len, ali, ctx, wenc);
    // ctxpre[n][col] = wenc[n, col>>9, :] @ W_enc[:, col] + b_enc:  8ct x 16ks
    skinny_k<<<128, 256, 0, stream>>>(wenc, W_enc, b_enc, cpre, HA_D, 7, 3, 4096, 1024);
    // ctx[n][j] = cpre[n,:] @ W_ctx[:, j] + b_ctx:  4ct x 32ks
    skinny_k<<<128, 256, 0, stream>>>(cpre, W_ctx, b_ctx, ctx, ENC_D, 3, 2, 2048, 0);
}